// Round 5
// baseline (98.882 us; speedup 1.0000x reference)
//
#include <hip/hip_runtime.h>

#define NNODE 1024
#define TT 12
#define NBT 48
#define CAP 128        // padded-CSR row capacity (max deg ~ Poisson(33); P(>128) ~ 1e-40)
#define WORDS 32       // 1024 bits / 32
#define CSRB 16        // CSR-builder blocks, 64 rows each

typedef __attribute__((ext_vector_type(8))) short bf16x8;
typedef __attribute__((ext_vector_type(4))) float f32x4;

// manual RNE float->bf16
__device__ __forceinline__ short bfh(float f) {
    unsigned int u = __float_as_uint(f);
    u = (u + 0x7fffu + ((u >> 16) & 1u)) >> 16;
    return (short)u;
}
__device__ __forceinline__ float bf2f(unsigned int v) {   // v = 16-bit payload
    return __uint_as_float(v << 16);
}

// ============ K1: fused CSR build (blocks 0..15) + MFMA projection ============

__global__ __launch_bounds__(256) void csr_and_h(const int* __restrict__ ei, int E,
                                                 int* __restrict__ deg,
                                                 int* __restrict__ col,
                                                 const float* __restrict__ x,
                                                 const float* __restrict__ W,
                                                 const float* __restrict__ a_l,
                                                 const float* __restrict__ a_r,
                                                 unsigned short* __restrict__ hbuf,
                                                 float* __restrict__ al,
                                                 float* __restrict__ ar) {
    __shared__ char smem[16896];           // CSR: 8KB bitmask | proj: 4 x 16x66 u16 tiles
    int tid = threadIdx.x, w = tid >> 6, lane = tid & 63;

    if (blockIdx.x < CSRB) {
        // ---- CSR: LDS bitmask for 64 rows; scan all edges; compact ----
        unsigned int* lbm = (unsigned int*)smem;
        for (int q = tid; q < 64 * WORDS; q += 256) lbm[q] = 0u;
        __syncthreads();
        int base = blockIdx.x * 64;
        for (int e = tid; e < E; e += 256) {
            int s = ei[e];
            unsigned int r = (unsigned int)(s - base);
            if (r < 64u) {
                int d2 = ei[E + e];
                atomicOr(&lbm[r * WORDS + (d2 >> 5)], 1u << (d2 & 31));
            }
        }
        __syncthreads();
        int half = lane >> 5, sub = lane & 31;
        for (int rr = 0; rr < 8; rr++) {      // 2 rows per wave-pass x 8
            int rloc = w * 16 + rr * 2 + half;
            int i = base + rloc;
            unsigned int word = lbm[rloc * WORDS + sub];
            int cnt = __popc(word), incl = cnt;
            #pragma unroll
            for (int o = 1; o < 32; o <<= 1) {
                int tv = __shfl_up(incl, o, 32);
                if (sub >= o) incl += tv;
            }
            int total = __shfl(incl, 31, 32);
            int excl = incl - cnt;
            if (sub == 0) deg[i] = total;
            int* outp = col + i * CAP + excl;
            int idx = 0, nb = sub * 32;
            while (word) { int bp = __ffs(word) - 1; word &= word - 1; outp[idx++] = nb + bp; }
        }
        return;
    }

    // ---- MFMA projection: wave computes h[n0..n0+16][0..64] for one bt ----
    int pb = blockIdx.x - CSRB;            // 0..767
    int bt = pb >> 4;
    int n0 = (pb & 15) * 64 + w * 16;
    int b = bt / TT, t = bt % TT;
    int m = lane & 15, kb = lane >> 4;

    // A frags: x[n0+m][k], k = kb*8+j (and +32)  [layout: row=lane&15, k=(lane>>4)*8+j]
    const float* xr = x + ((size_t)(b * NNODE + n0 + m) * TT + t) * 64 + kb * 8;
    float4 x0 = *(const float4*)xr;
    float4 x1 = *(const float4*)(xr + 4);
    float4 x2 = *(const float4*)(xr + 32);
    float4 x3 = *(const float4*)(xr + 36);
    bf16x8 af0, af1;
    af0[0] = bfh(x0.x); af0[1] = bfh(x0.y); af0[2] = bfh(x0.z); af0[3] = bfh(x0.w);
    af0[4] = bfh(x1.x); af0[5] = bfh(x1.y); af0[6] = bfh(x1.z); af0[7] = bfh(x1.w);
    af1[0] = bfh(x2.x); af1[1] = bfh(x2.y); af1[2] = bfh(x2.z); af1[3] = bfh(x2.w);
    af1[4] = bfh(x3.x); af1[5] = bfh(x3.y); af1[6] = bfh(x3.z); af1[7] = bfh(x3.w);

    f32x4 acc[4];
    float alv[4], arv[4];
    #pragma unroll
    for (int nt = 0; nt < 4; nt++) {
        acc[nt] = (f32x4){0.f, 0.f, 0.f, 0.f};
        // B frags: B[k][n] = W[nt*16+n][k]; lane holds n=lane&15, k=(lane>>4)*8+j
        const float* wr_ = W + (nt * 16 + m) * 64 + kb * 8;
        float4 w0 = *(const float4*)wr_;
        float4 w1 = *(const float4*)(wr_ + 4);
        float4 w2 = *(const float4*)(wr_ + 32);
        float4 w3 = *(const float4*)(wr_ + 36);
        bf16x8 bf0, bf1;
        bf0[0] = bfh(w0.x); bf0[1] = bfh(w0.y); bf0[2] = bfh(w0.z); bf0[3] = bfh(w0.w);
        bf0[4] = bfh(w1.x); bf0[5] = bfh(w1.y); bf0[6] = bfh(w1.z); bf0[7] = bfh(w1.w);
        bf1[0] = bfh(w2.x); bf1[1] = bfh(w2.y); bf1[2] = bfh(w2.z); bf1[3] = bfh(w2.w);
        bf1[4] = bfh(w3.x); bf1[5] = bfh(w3.y); bf1[6] = bfh(w3.z); bf1[7] = bfh(w3.w);
        acc[nt] = __builtin_amdgcn_mfma_f32_16x16x32_bf16(af0, bf0, acc[nt], 0, 0, 0);
        acc[nt] = __builtin_amdgcn_mfma_f32_16x16x32_bf16(af1, bf1, acc[nt], 0, 0, 0);
        alv[nt] = a_l[nt * 16 + m];
        arv[nt] = a_r[nt * 16 + m];
    }

    // al/ar: D[row][col]: col=lane&15(+16*nt), row=(lane>>4)*4+j. Reduce over cols.
    #pragma unroll
    for (int j = 0; j < 4; j++) {
        float sl = acc[0][j] * alv[0] + acc[1][j] * alv[1] + acc[2][j] * alv[2] + acc[3][j] * alv[3];
        float sr = acc[0][j] * arv[0] + acc[1][j] * arv[1] + acc[2][j] * arv[2] + acc[3][j] * arv[3];
        #pragma unroll
        for (int o = 1; o < 16; o <<= 1) {   // reduce the 16 lanes sharing kb
            sl += __shfl_xor(sl, o);
            sr += __shfl_xor(sr, o);
        }
        if (m == 0) {
            int row = n0 + kb * 4 + j;
            al[bt * NNODE + row] = sl;
            ar[bt * NNODE + row] = sr;
        }
    }

    // h -> hbuf (bf16 row-major) via per-wave LDS transpose tile [16][66]
    unsigned short* ht = (unsigned short*)smem + (size_t)w * (16 * 66);
    #pragma unroll
    for (int nt = 0; nt < 4; nt++)
        #pragma unroll
        for (int j = 0; j < 4; j++)
            ht[(kb * 4 + j) * 66 + nt * 16 + m] = (unsigned short)bfh(acc[nt][j]);
    // same-wave LDS write->read: compiler-inserted lgkmcnt suffices
    unsigned int* hb32 = (unsigned int*)(hbuf + ((size_t)bt * NNODE + n0) * 64);
    int half = lane >> 5, sub = lane & 31;
    #pragma unroll
    for (int rr = 0; rr < 8; rr++) {
        int row = rr * 2 + half;
        unsigned int lo = ht[row * 66 + sub * 2];
        unsigned int hi = ht[row * 66 + sub * 2 + 1];
        hb32[row * 32 + sub] = (lo & 0xffffu) | (hi << 16);
    }
}

// ============ K2: softmax + aggregate + bias + gelu ============
// block = (row i, bt-group g of 6); blockIdx = i*8+g -> XCD round-robin pins
// group g to XCD g; per-XCD hbuf working set 6*128KB = 768KB (fits 4MB L2).

__global__ __launch_bounds__(384) void aggregate(const unsigned short* __restrict__ hbuf,
                                                 const float* __restrict__ al,
                                                 const float* __restrict__ ar,
                                                 const int* __restrict__ deg,
                                                 const int* __restrict__ col,
                                                 const float* __restrict__ bias,
                                                 float* __restrict__ out) {
    __shared__ int2 pl[6][CAP];
    int w = threadIdx.x >> 6, lane = threadIdx.x & 63;
    int half = lane >> 5, sub = lane & 31;
    int i = blockIdx.x >> 3;
    int g = blockIdx.x & 7;
    int bt = g * 6 + w;
    int b = bt / TT, t = bt % TT;

    int d = deg[i];
    const int* ci = col + i * CAP;
    float ali = al[bt * NNODE + i];
    const float* arb = ar + bt * NNODE;

    int c0 = 0, c1 = 0;
    float e0 = -1e30f, e1 = -1e30f;
    if (lane < d) {
        c0 = ci[lane];
        float e = ali + arb[c0];
        e0 = (e >= 0.f) ? e : 0.2f * e;
    }
    if (lane + 64 < d) {
        c1 = ci[lane + 64];
        float e = ali + arb[c1];
        e1 = (e >= 0.f) ? e : 0.2f * e;
    }
    float m = fmaxf(e0, e1);
    #pragma unroll
    for (int o = 32; o > 0; o >>= 1) m = fmaxf(m, __shfl_xor(m, o));
    float p0 = (lane < d) ? __expf(e0 - m) : 0.f;
    float p1 = (lane + 64 < d) ? __expf(e1 - m) : 0.f;
    float s = p0 + p1;
    #pragma unroll
    for (int o = 32; o > 0; o >>= 1) s += __shfl_xor(s, o);
    if (lane < d) pl[w][lane] = make_int2(c0, __float_as_int(p0));
    if (lane + 64 < d) pl[w][lane + 64] = make_int2(c1, __float_as_int(p1));
    // per-wave private LDS: within-wave lgkmcnt ordering suffices, no barrier

    const unsigned short* hb = hbuf + (size_t)bt * NNODE * 64;
    float a0 = 0.f, a1 = 0.f;
    #pragma unroll 8
    for (int k = 0; k < d; k += 2) {
        int kk = k + half;
        int2 cp = (kk < d) ? pl[w][kk] : make_int2(0, 0);   // int 0 == 0.0f
        unsigned int hv = *(const unsigned int*)(hb + cp.x * 64 + 2 * sub);
        float pv = __int_as_float(cp.y);
        a0 = fmaf(pv, bf2f(hv & 0xffffu), a0);
        a1 = fmaf(pv, bf2f(hv >> 16), a1);
    }
    a0 += __shfl_xor(a0, 32);
    a1 += __shfl_xor(a1, 32);

    float inv = 1.f / s;
    float2 bb = ((const float2*)bias)[sub];
    float v0 = a0 * inv + bb.x;
    float v1 = a1 * inv + bb.y;
    float g0 = 0.5f * v0 * (1.f + erff(v0 * 0.70710678118654752f));
    float g1 = 0.5f * v1 * (1.f + erff(v1 * 0.70710678118654752f));
    if (half == 0) {
        float2* op = (float2*)(out + ((size_t)(b * NNODE + i) * TT + t) * 64);
        op[sub] = make_float2(g0, g1);
    }
}

// ---------------- launch ----------------

extern "C" void kernel_launch(void* const* d_in, const int* in_sizes, int n_in,
                              void* d_out, int out_size, void* d_ws, size_t ws_size,
                              hipStream_t stream) {
    const float* x    = (const float*)d_in[0];
    const int*   ei   = (const int*)d_in[1];
    const float* W    = (const float*)d_in[2];
    const float* a_l  = (const float*)d_in[3];
    const float* a_r  = (const float*)d_in[4];
    const float* bias = (const float*)d_in[5];
    float* out = (float*)d_out;
    int E = in_sizes[1] / 2;     // 33792

    char* ws = (char*)d_ws;
    int* deg = (int*)ws;                                           // 4 KB
    int* col = (int*)(ws + 8192);                                  // 512 KB
    unsigned short* hbuf = (unsigned short*)(ws + 8192 + (512 << 10));   // 6.3 MB bf16
    float* al = (float*)(ws + 8192 + (512 << 10) + (size_t)NBT * NNODE * 64 * 2);
    float* ar = al + NBT * NNODE;

    csr_and_h<<<CSRB + NBT * 16, 256, 0, stream>>>(ei, E, deg, col, x, W, a_l, a_r, hbuf, al, ar);
    aggregate<<<NNODE * 8, 384, 0, stream>>>(hbuf, al, ar, deg, col, bias, out);
}

// Round 6
// 57.172 us; speedup vs baseline: 1.7296x; 1.7296x over previous
//
#include <hip/hip_runtime.h>

#define NNODE 1024
#define TT 12
#define NBT 48
#define CAP 128        // padded-CSR row capacity (max deg ~ Poisson(33); P(>128) ~ 1e-40)
#define WORDS 32       // 1024 bits / 32

typedef __attribute__((ext_vector_type(8))) short bf16x8;
typedef __attribute__((ext_vector_type(4))) float f32x4;

// manual RNE float->bf16
__device__ __forceinline__ short bfh(float f) {
    unsigned int u = __float_as_uint(f);
    u = (u + 0x7fffu + ((u >> 16) & 1u)) >> 16;
    return (short)u;
}
__device__ __forceinline__ float bf2f(unsigned int v) {   // v = 16-bit payload
    return __uint_as_float(v << 16);
}

// ---------------- zero 128 KB bitmask ----------------

__global__ __launch_bounds__(256) void zero_bm(uint4* __restrict__ bm) {
    bm[blockIdx.x * 256 + threadIdx.x] = uint4{0, 0, 0, 0};
}

// ---------------- edge scatter into bitmask (full edge parallelism) --------

__global__ __launch_bounds__(256) void scatter_adj(const int* __restrict__ ei, int E,
                                                   unsigned int* __restrict__ bm) {
    int e = blockIdx.x * 256 + threadIdx.x;
    if (e < E) {
        int s = ei[e];
        int d = ei[E + e];
        atomicOr(&bm[s * WORDS + (d >> 5)], 1u << (d & 31));
    }
}

// ======== K2: CSR build from bitmask (blocks 0..127) + MFMA projection ========

__global__ __launch_bounds__(256) void csr_and_h(const unsigned int* __restrict__ bm,
                                                 int* __restrict__ deg,
                                                 int* __restrict__ col,
                                                 const float* __restrict__ x,
                                                 const float* __restrict__ W,
                                                 const float* __restrict__ a_l,
                                                 const float* __restrict__ a_r,
                                                 unsigned short* __restrict__ hbuf,
                                                 float* __restrict__ al,
                                                 float* __restrict__ ar) {
    __shared__ __align__(16) char smem[16896];   // proj: 4 x 16x66 u16 transpose tiles
    int tid = threadIdx.x, w = tid >> 6, lane = tid & 63;
    int half = lane >> 5, sub = lane & 31;

    if (blockIdx.x < 128) {
        // ---- CSR: 2 rows per wave, 32-lane segments; 8 rows per block ----
        int i = blockIdx.x * 8 + w * 2 + half;
        unsigned int word = bm[i * WORDS + sub];
        int cnt = __popc(word);
        int incl = cnt;
        #pragma unroll
        for (int o = 1; o < 32; o <<= 1) {
            int tv = __shfl_up(incl, o, 32);
            if (sub >= o) incl += tv;
        }
        int total = __shfl(incl, 31, 32);
        int excl = incl - cnt;
        if (sub == 0) deg[i] = total;
        int* outp = col + i * CAP + excl;
        int idx = 0, nb = sub * 32;
        while (word) {
            int bp = __ffs(word) - 1;
            word &= word - 1;
            outp[idx++] = nb + bp;
        }
        return;
    }

    // ---- MFMA projection: wave computes h[n0..n0+16][0..64] for one bt ----
    int pb = blockIdx.x - 128;             // 0..767
    int bt = pb >> 4;
    int n0 = (pb & 15) * 64 + w * 16;
    int b = bt / TT, t = bt % TT;
    int m = lane & 15, kb = lane >> 4;

    // A frags: x[n0+m][k], k = kb*8+j (and +32)  [layout: row=lane&15, k=(lane>>4)*8+j]
    const float* xr = x + ((size_t)(b * NNODE + n0 + m) * TT + t) * 64 + kb * 8;
    float4 x0 = *(const float4*)xr;
    float4 x1 = *(const float4*)(xr + 4);
    float4 x2 = *(const float4*)(xr + 32);
    float4 x3 = *(const float4*)(xr + 36);
    bf16x8 af0, af1;
    af0[0] = bfh(x0.x); af0[1] = bfh(x0.y); af0[2] = bfh(x0.z); af0[3] = bfh(x0.w);
    af0[4] = bfh(x1.x); af0[5] = bfh(x1.y); af0[6] = bfh(x1.z); af0[7] = bfh(x1.w);
    af1[0] = bfh(x2.x); af1[1] = bfh(x2.y); af1[2] = bfh(x2.z); af1[3] = bfh(x2.w);
    af1[4] = bfh(x3.x); af1[5] = bfh(x3.y); af1[6] = bfh(x3.z); af1[7] = bfh(x3.w);

    f32x4 acc[4];
    float alv[4], arv[4];
    #pragma unroll
    for (int nt = 0; nt < 4; nt++) {
        acc[nt] = (f32x4){0.f, 0.f, 0.f, 0.f};
        // B frags: B[k][n] = W[nt*16+n][k]; lane holds n=lane&15, k=(lane>>4)*8+j
        const float* wr_ = W + (nt * 16 + m) * 64 + kb * 8;
        float4 w0 = *(const float4*)wr_;
        float4 w1 = *(const float4*)(wr_ + 4);
        float4 w2 = *(const float4*)(wr_ + 32);
        float4 w3 = *(const float4*)(wr_ + 36);
        bf16x8 bf0, bf1;
        bf0[0] = bfh(w0.x); bf0[1] = bfh(w0.y); bf0[2] = bfh(w0.z); bf0[3] = bfh(w0.w);
        bf0[4] = bfh(w1.x); bf0[5] = bfh(w1.y); bf0[6] = bfh(w1.z); bf0[7] = bfh(w1.w);
        bf1[0] = bfh(w2.x); bf1[1] = bfh(w2.y); bf1[2] = bfh(w2.z); bf1[3] = bfh(w2.w);
        bf1[4] = bfh(w3.x); bf1[5] = bfh(w3.y); bf1[6] = bfh(w3.z); bf1[7] = bfh(w3.w);
        acc[nt] = __builtin_amdgcn_mfma_f32_16x16x32_bf16(af0, bf0, acc[nt], 0, 0, 0);
        acc[nt] = __builtin_amdgcn_mfma_f32_16x16x32_bf16(af1, bf1, acc[nt], 0, 0, 0);
        alv[nt] = a_l[nt * 16 + m];
        arv[nt] = a_r[nt * 16 + m];
    }

    // al/ar: D[row][col]: col=lane&15(+16*nt), row=(lane>>4)*4+j. Reduce over cols.
    #pragma unroll
    for (int j = 0; j < 4; j++) {
        float sl = acc[0][j] * alv[0] + acc[1][j] * alv[1] + acc[2][j] * alv[2] + acc[3][j] * alv[3];
        float sr = acc[0][j] * arv[0] + acc[1][j] * arv[1] + acc[2][j] * arv[2] + acc[3][j] * arv[3];
        #pragma unroll
        for (int o = 1; o < 16; o <<= 1) {   // reduce the 16 lanes sharing kb
            sl += __shfl_xor(sl, o);
            sr += __shfl_xor(sr, o);
        }
        if (m == 0) {
            int row = n0 + kb * 4 + j;
            al[bt * NNODE + row] = sl;
            ar[bt * NNODE + row] = sr;
        }
    }

    // h -> hbuf (bf16 row-major) via per-wave LDS transpose tile [16][66]
    unsigned short* ht = (unsigned short*)smem + (size_t)w * (16 * 66);
    #pragma unroll
    for (int nt = 0; nt < 4; nt++)
        #pragma unroll
        for (int j = 0; j < 4; j++)
            ht[(kb * 4 + j) * 66 + nt * 16 + m] = (unsigned short)bfh(acc[nt][j]);
    // same-wave LDS write->read: compiler-inserted lgkmcnt suffices
    unsigned int* hb32 = (unsigned int*)(hbuf + ((size_t)bt * NNODE + n0) * 64);
    #pragma unroll
    for (int rr = 0; rr < 8; rr++) {
        int row = rr * 2 + half;
        unsigned int lo = ht[row * 66 + sub * 2];
        unsigned int hi = ht[row * 66 + sub * 2 + 1];
        hb32[row * 32 + sub] = (lo & 0xffffu) | (hi << 16);
    }
}

// ============ K3: softmax + aggregate + bias + gelu ============
// block = (row i, bt-group g of 6); blockIdx = i*8+g -> XCD round-robin pins
// group g to XCD g; per-XCD hbuf working set 6*128KB = 768KB (fits 4MB L2).

__global__ __launch_bounds__(384) void aggregate(const unsigned short* __restrict__ hbuf,
                                                 const float* __restrict__ al,
                                                 const float* __restrict__ ar,
                                                 const int* __restrict__ deg,
                                                 const int* __restrict__ col,
                                                 const float* __restrict__ bias,
                                                 float* __restrict__ out) {
    __shared__ int2 pl[6][CAP];
    int w = threadIdx.x >> 6, lane = threadIdx.x & 63;
    int half = lane >> 5, sub = lane & 31;
    int i = blockIdx.x >> 3;
    int g = blockIdx.x & 7;
    int bt = g * 6 + w;
    int b = bt / TT, t = bt % TT;

    int d = deg[i];
    const int* ci = col + i * CAP;
    float ali = al[bt * NNODE + i];
    const float* arb = ar + bt * NNODE;

    int c0 = 0, c1 = 0;
    float e0 = -1e30f, e1 = -1e30f;
    if (lane < d) {
        c0 = ci[lane];
        float e = ali + arb[c0];
        e0 = (e >= 0.f) ? e : 0.2f * e;
    }
    if (lane + 64 < d) {
        c1 = ci[lane + 64];
        float e = ali + arb[c1];
        e1 = (e >= 0.f) ? e : 0.2f * e;
    }
    float m = fmaxf(e0, e1);
    #pragma unroll
    for (int o = 32; o > 0; o >>= 1) m = fmaxf(m, __shfl_xor(m, o));
    float p0 = (lane < d) ? __expf(e0 - m) : 0.f;
    float p1 = (lane + 64 < d) ? __expf(e1 - m) : 0.f;
    float s = p0 + p1;
    #pragma unroll
    for (int o = 32; o > 0; o >>= 1) s += __shfl_xor(s, o);
    if (lane < d) pl[w][lane] = make_int2(c0, __float_as_int(p0));
    if (lane + 64 < d) pl[w][lane + 64] = make_int2(c1, __float_as_int(p1));
    // per-wave private LDS: within-wave lgkmcnt ordering suffices, no barrier

    const unsigned short* hb = hbuf + (size_t)bt * NNODE * 64;
    float a0 = 0.f, a1 = 0.f;
    #pragma unroll 8
    for (int k = 0; k < d; k += 2) {
        int kk = k + half;
        int2 cp = (kk < d) ? pl[w][kk] : make_int2(0, 0);   // int 0 == 0.0f
        unsigned int hv = *(const unsigned int*)(hb + cp.x * 64 + 2 * sub);
        float pv = __int_as_float(cp.y);
        a0 = fmaf(pv, bf2f(hv & 0xffffu), a0);
        a1 = fmaf(pv, bf2f(hv >> 16), a1);
    }
    a0 += __shfl_xor(a0, 32);
    a1 += __shfl_xor(a1, 32);

    float inv = 1.f / s;
    float2 bb = ((const float2*)bias)[sub];
    float v0 = a0 * inv + bb.x;
    float v1 = a1 * inv + bb.y;
    float g0 = 0.5f * v0 * (1.f + erff(v0 * 0.70710678118654752f));
    float g1 = 0.5f * v1 * (1.f + erff(v1 * 0.70710678118654752f));
    if (half == 0) {
        float2* op = (float2*)(out + ((size_t)(b * NNODE + i) * TT + t) * 64);
        op[sub] = make_float2(g0, g1);
    }
}

// ---------------- launch ----------------

extern "C" void kernel_launch(void* const* d_in, const int* in_sizes, int n_in,
                              void* d_out, int out_size, void* d_ws, size_t ws_size,
                              hipStream_t stream) {
    const float* x    = (const float*)d_in[0];
    const int*   ei   = (const int*)d_in[1];
    const float* W    = (const float*)d_in[2];
    const float* a_l  = (const float*)d_in[3];
    const float* a_r  = (const float*)d_in[4];
    const float* bias = (const float*)d_in[5];
    float* out = (float*)d_out;
    int E = in_sizes[1] / 2;     // 33792

    char* ws = (char*)d_ws;
    unsigned int* bm = (unsigned int*)ws;                          // 128 KB
    int* deg = (int*)(ws + (128 << 10));                           // 4 KB
    int* col = (int*)(ws + (128 << 10) + 8192);                    // 512 KB
    unsigned short* hbuf = (unsigned short*)(ws + (1 << 20));      // 6.3 MB bf16
    float* al = (float*)(ws + (1 << 20) + (size_t)NBT * NNODE * 64 * 2);
    float* ar = al + NBT * NNODE;

    zero_bm<<<32, 256, 0, stream>>>((uint4*)bm);
    scatter_adj<<<(E + 255) / 256, 256, 0, stream>>>(ei, E, bm);
    csr_and_h<<<128 + NBT * 16, 256, 0, stream>>>(bm, deg, col, x, W, a_l, a_r, hbuf, al, ar);
    aggregate<<<NNODE * 8, 384, 0, stream>>>(hbuf, al, ar, deg, col, bias, out);
}

// Round 7
// 55.653 us; speedup vs baseline: 1.7767x; 1.0273x over previous
//
#include <hip/hip_runtime.h>

#define NNODE 1024
#define TT 12
#define NBT 48
#define CAP 128        // padded-CSR row capacity (max deg ~ Poisson(33); P(>128) ~ 1e-40)
#define WORDS 32       // 1024 bits / 32

typedef __attribute__((ext_vector_type(8))) short bf16x8;
typedef __attribute__((ext_vector_type(4))) float f32x4;

// manual RNE float->bf16
__device__ __forceinline__ short bfh(float f) {
    unsigned int u = __float_as_uint(f);
    u = (u + 0x7fffu + ((u >> 16) & 1u)) >> 16;
    return (short)u;
}
__device__ __forceinline__ float bf2f(unsigned int v) {   // v = 16-bit payload
    return __uint_as_float(v << 16);
}

// ---------------- zero 128 KB bitmask ----------------

__global__ __launch_bounds__(256) void zero_bm(uint4* __restrict__ bm) {
    bm[blockIdx.x * 256 + threadIdx.x] = uint4{0, 0, 0, 0};
}

// ---------------- edge scatter into bitmask (full edge parallelism) --------

__global__ __launch_bounds__(256) void scatter_adj(const int* __restrict__ ei, int E,
                                                   unsigned int* __restrict__ bm) {
    int e = blockIdx.x * 256 + threadIdx.x;
    if (e < E) {
        int s = ei[e];
        int d = ei[E + e];
        atomicOr(&bm[s * WORDS + (d >> 5)], 1u << (d & 31));
    }
}

// ======== K2: CSR build from bitmask (blocks 0..127) + MFMA projection ========

__global__ __launch_bounds__(256) void csr_and_h(const unsigned int* __restrict__ bm,
                                                 int* __restrict__ deg,
                                                 int* __restrict__ col,
                                                 const float* __restrict__ x,
                                                 const float* __restrict__ W,
                                                 const float* __restrict__ a_l,
                                                 const float* __restrict__ a_r,
                                                 unsigned short* __restrict__ hbuf,
                                                 float* __restrict__ al,
                                                 float* __restrict__ ar) {
    __shared__ __align__(16) char smem[16896];   // proj: 4 x 16x66 u16 transpose tiles
    int tid = threadIdx.x, w = tid >> 6, lane = tid & 63;
    int half = lane >> 5, sub = lane & 31;

    if (blockIdx.x < 128) {
        // ---- CSR: 2 rows per wave, 32-lane segments; 8 rows per block ----
        int i = blockIdx.x * 8 + w * 2 + half;
        unsigned int word = bm[i * WORDS + sub];
        int cnt = __popc(word);
        int incl = cnt;
        #pragma unroll
        for (int o = 1; o < 32; o <<= 1) {
            int tv = __shfl_up(incl, o, 32);
            if (sub >= o) incl += tv;
        }
        int total = __shfl(incl, 31, 32);
        int excl = incl - cnt;
        if (sub == 0) deg[i] = total;
        int* outp = col + i * CAP + excl;
        int idx = 0, nb = sub * 32;
        while (word) {
            int bp = __ffs(word) - 1;
            word &= word - 1;
            outp[idx++] = nb + bp;
        }
        return;
    }

    // ---- MFMA projection: wave computes h[n0..n0+16][0..64] for one bt ----
    int pb = blockIdx.x - 128;             // 0..767
    int bt = pb >> 4;
    int n0 = (pb & 15) * 64 + w * 16;
    int b = bt / TT, t = bt % TT;
    int m = lane & 15, kb = lane >> 4;

    // A frags: x[n0+m][k], k = kb*8+j (and +32)  [layout: row=lane&15, k=(lane>>4)*8+j]
    const float* xr = x + ((size_t)(b * NNODE + n0 + m) * TT + t) * 64 + kb * 8;
    float4 x0 = *(const float4*)xr;
    float4 x1 = *(const float4*)(xr + 4);
    float4 x2 = *(const float4*)(xr + 32);
    float4 x3 = *(const float4*)(xr + 36);
    bf16x8 af0, af1;
    af0[0] = bfh(x0.x); af0[1] = bfh(x0.y); af0[2] = bfh(x0.z); af0[3] = bfh(x0.w);
    af0[4] = bfh(x1.x); af0[5] = bfh(x1.y); af0[6] = bfh(x1.z); af0[7] = bfh(x1.w);
    af1[0] = bfh(x2.x); af1[1] = bfh(x2.y); af1[2] = bfh(x2.z); af1[3] = bfh(x2.w);
    af1[4] = bfh(x3.x); af1[5] = bfh(x3.y); af1[6] = bfh(x3.z); af1[7] = bfh(x3.w);

    f32x4 acc[4];
    float alv[4], arv[4];
    #pragma unroll
    for (int nt = 0; nt < 4; nt++) {
        acc[nt] = (f32x4){0.f, 0.f, 0.f, 0.f};
        // B frags: B[k][n] = W[nt*16+n][k]; lane holds n=lane&15, k=(lane>>4)*8+j
        const float* wr_ = W + (nt * 16 + m) * 64 + kb * 8;
        float4 w0 = *(const float4*)wr_;
        float4 w1 = *(const float4*)(wr_ + 4);
        float4 w2 = *(const float4*)(wr_ + 32);
        float4 w3 = *(const float4*)(wr_ + 36);
        bf16x8 bf0, bf1;
        bf0[0] = bfh(w0.x); bf0[1] = bfh(w0.y); bf0[2] = bfh(w0.z); bf0[3] = bfh(w0.w);
        bf0[4] = bfh(w1.x); bf0[5] = bfh(w1.y); bf0[6] = bfh(w1.z); bf0[7] = bfh(w1.w);
        bf1[0] = bfh(w2.x); bf1[1] = bfh(w2.y); bf1[2] = bfh(w2.z); bf1[3] = bfh(w2.w);
        bf1[4] = bfh(w3.x); bf1[5] = bfh(w3.y); bf1[6] = bfh(w3.z); bf1[7] = bfh(w3.w);
        acc[nt] = __builtin_amdgcn_mfma_f32_16x16x32_bf16(af0, bf0, acc[nt], 0, 0, 0);
        acc[nt] = __builtin_amdgcn_mfma_f32_16x16x32_bf16(af1, bf1, acc[nt], 0, 0, 0);
        alv[nt] = a_l[nt * 16 + m];
        arv[nt] = a_r[nt * 16 + m];
    }

    // al/ar: D[row][col]: col=lane&15(+16*nt), row=(lane>>4)*4+j. Reduce over cols.
    #pragma unroll
    for (int j = 0; j < 4; j++) {
        float sl = acc[0][j] * alv[0] + acc[1][j] * alv[1] + acc[2][j] * alv[2] + acc[3][j] * alv[3];
        float sr = acc[0][j] * arv[0] + acc[1][j] * arv[1] + acc[2][j] * arv[2] + acc[3][j] * arv[3];
        #pragma unroll
        for (int o = 1; o < 16; o <<= 1) {   // reduce the 16 lanes sharing kb
            sl += __shfl_xor(sl, o);
            sr += __shfl_xor(sr, o);
        }
        if (m == 0) {
            int row = n0 + kb * 4 + j;
            al[bt * NNODE + row] = sl;
            ar[bt * NNODE + row] = sr;
        }
    }

    // h -> hbuf (bf16 row-major) via per-wave LDS transpose tile [16][66]
    unsigned short* ht = (unsigned short*)smem + (size_t)w * (16 * 66);
    #pragma unroll
    for (int nt = 0; nt < 4; nt++)
        #pragma unroll
        for (int j = 0; j < 4; j++)
            ht[(kb * 4 + j) * 66 + nt * 16 + m] = (unsigned short)bfh(acc[nt][j]);
    // same-wave LDS write->read: compiler-inserted lgkmcnt suffices
    unsigned int* hb32 = (unsigned int*)(hbuf + ((size_t)bt * NNODE + n0) * 64);
    #pragma unroll
    for (int rr = 0; rr < 8; rr++) {
        int row = rr * 2 + half;
        unsigned int lo = ht[row * 66 + sub * 2];
        unsigned int hi = ht[row * 66 + sub * 2 + 1];
        hb32[row * 32 + sub] = (lo & 0xffffu) | (hi << 16);
    }
}

// ============ K3: softmax + aggregate + bias + gelu ============
// block = (row i, bt-group g of 6); blockIdx = i*8+g -> XCD round-robin pins
// group g to XCD g; per-XCD hbuf working set 6*128KB = 768KB (fits 4MB L2).
// PV phase: quarter-waves split neighbors (4 rows/iter); lane covers 4 bf16
// dims via uint2 load -> 2x memory-level parallelism vs half-wave/uint.

__global__ __launch_bounds__(384) void aggregate(const unsigned short* __restrict__ hbuf,
                                                 const float* __restrict__ al,
                                                 const float* __restrict__ ar,
                                                 const int* __restrict__ deg,
                                                 const int* __restrict__ col,
                                                 const float* __restrict__ bias,
                                                 float* __restrict__ out) {
    __shared__ int2 pl[6][CAP];
    int w = threadIdx.x >> 6, lane = threadIdx.x & 63;
    int i = blockIdx.x >> 3;
    int g = blockIdx.x & 7;
    int bt = g * 6 + w;
    int b = bt / TT, t = bt % TT;

    int d = deg[i];
    const int* ci = col + i * CAP;
    float ali = al[bt * NNODE + i];
    const float* arb = ar + bt * NNODE;

    int c0 = 0, c1 = 0;
    float e0 = -1e30f, e1 = -1e30f;
    if (lane < d) {
        c0 = ci[lane];
        float e = ali + arb[c0];
        e0 = (e >= 0.f) ? e : 0.2f * e;
    }
    if (lane + 64 < d) {
        c1 = ci[lane + 64];
        float e = ali + arb[c1];
        e1 = (e >= 0.f) ? e : 0.2f * e;
    }
    float m = fmaxf(e0, e1);
    #pragma unroll
    for (int o = 32; o > 0; o >>= 1) m = fmaxf(m, __shfl_xor(m, o));
    float p0 = (lane < d) ? __expf(e0 - m) : 0.f;
    float p1 = (lane + 64 < d) ? __expf(e1 - m) : 0.f;
    float s = p0 + p1;
    #pragma unroll
    for (int o = 32; o > 0; o >>= 1) s += __shfl_xor(s, o);
    if (lane < d) pl[w][lane] = make_int2(c0, __float_as_int(p0));
    if (lane + 64 < d) pl[w][lane + 64] = make_int2(c1, __float_as_int(p1));
    // per-wave private LDS: within-wave lgkmcnt ordering suffices, no barrier

    const unsigned short* hb = hbuf + (size_t)bt * NNODE * 64;
    int quarter = lane >> 4, q16 = lane & 15;
    float a0 = 0.f, a1 = 0.f, a2 = 0.f, a3 = 0.f;
    #pragma unroll 2
    for (int k = 0; k < d; k += 4) {
        int kk = k + quarter;
        int2 cp = (kk < d) ? pl[w][kk] : make_int2(0, 0);   // row 0 read, p = 0.0f
        uint2 hv = *(const uint2*)(hb + cp.x * 64 + q16 * 4);
        float pv = __int_as_float(cp.y);
        a0 = fmaf(pv, bf2f(hv.x & 0xffffu), a0);
        a1 = fmaf(pv, bf2f(hv.x >> 16), a1);
        a2 = fmaf(pv, bf2f(hv.y & 0xffffu), a2);
        a3 = fmaf(pv, bf2f(hv.y >> 16), a3);
    }
    a0 += __shfl_xor(a0, 16); a0 += __shfl_xor(a0, 32);
    a1 += __shfl_xor(a1, 16); a1 += __shfl_xor(a1, 32);
    a2 += __shfl_xor(a2, 16); a2 += __shfl_xor(a2, 32);
    a3 += __shfl_xor(a3, 16); a3 += __shfl_xor(a3, 32);

    if (quarter == 0) {
        float inv = 1.f / s;
        float4 bb = ((const float4*)bias)[q16];
        float v0 = a0 * inv + bb.x;
        float v1 = a1 * inv + bb.y;
        float v2 = a2 * inv + bb.z;
        float v3 = a3 * inv + bb.w;
        const float c = 0.70710678118654752f;
        float4 gv;
        gv.x = 0.5f * v0 * (1.f + erff(v0 * c));
        gv.y = 0.5f * v1 * (1.f + erff(v1 * c));
        gv.z = 0.5f * v2 * (1.f + erff(v2 * c));
        gv.w = 0.5f * v3 * (1.f + erff(v3 * c));
        float4* op = (float4*)(out + ((size_t)(b * NNODE + i) * TT + t) * 64);
        op[q16] = gv;
    }
}

// ---------------- launch ----------------

extern "C" void kernel_launch(void* const* d_in, const int* in_sizes, int n_in,
                              void* d_out, int out_size, void* d_ws, size_t ws_size,
                              hipStream_t stream) {
    const float* x    = (const float*)d_in[0];
    const int*   ei   = (const int*)d_in[1];
    const float* W    = (const float*)d_in[2];
    const float* a_l  = (const float*)d_in[3];
    const float* a_r  = (const float*)d_in[4];
    const float* bias = (const float*)d_in[5];
    float* out = (float*)d_out;
    int E = in_sizes[1] / 2;     // 33792

    char* ws = (char*)d_ws;
    unsigned int* bm = (unsigned int*)ws;                          // 128 KB
    int* deg = (int*)(ws + (128 << 10));                           // 4 KB
    int* col = (int*)(ws + (128 << 10) + 8192);                    // 512 KB
    unsigned short* hbuf = (unsigned short*)(ws + (1 << 20));      // 6.3 MB bf16
    float* al = (float*)(ws + (1 << 20) + (size_t)NBT * NNODE * 64 * 2);
    float* ar = al + NBT * NNODE;

    zero_bm<<<32, 256, 0, stream>>>((uint4*)bm);
    scatter_adj<<<(E + 255) / 256, 256, 0, stream>>>(ei, E, bm);
    csr_and_h<<<128 + NBT * 16, 256, 0, stream>>>(bm, deg, col, x, W, a_l, a_r, hbuf, al, ar);
    aggregate<<<NNODE * 8, 384, 0, stream>>>(hbuf, al, ar, deg, col, bias, out);
}